// Round 6
// baseline (164.422 us; speedup 1.0000x reference)
//
#include <hip/hip_runtime.h>
#include <stdint.h>

typedef unsigned short u16;
typedef uint32_t u32;
typedef short bf16x8 __attribute__((ext_vector_type(8)));
typedef float f32x4 __attribute__((ext_vector_type(4)));

#define PI_F 3.14159265358979323846f
#define NSAMP 512000
#define MROWS 16000
#define K2 512
#define NKOUT 512
#define NBLK 500

__device__ __forceinline__ u16 f2bf(float f) {
  uint32_t x = __float_as_uint(f);
  return (u16)((x + 0x7fffu + ((x >> 16) & 1u)) >> 16);  // RNE (host-side tables only)
}
__device__ __forceinline__ float bf2f(u16 u) {
  return __uint_as_float(((uint32_t)u) << 16);
}

// Folded basis Bf[k][m], k,m in [0,512). theta = pi*((2n+513)(2k+1) mod 4096)/2048, n=m&255.
// m<256: cos(theta); m>=256: -(-1)^k sin(theta). Scale 1/16 folded in. Split bf16 hi+lo.
__global__ void build_basis(u16* __restrict__ bt_hi, u16* __restrict__ bt_lo) {
  int idx = blockIdx.x * 256 + threadIdx.x;  // 512*512
  int k = idx >> 9, m = idx & 511;
  int n = m & 255;
  int P = ((2 * n + 513) * (2 * k + 1)) & 4095;
  float ang = PI_F * (float)P / 2048.0f;
  float v = (m < 256) ? cosf(ang) : ((k & 1) ? sinf(ang) : -sinf(ang));
  v *= 0.0625f;
  u16 hi = f2bf(v);
  bt_hi[idx] = hi;
  bt_lo[idx] = f2bf(v - bf2f(hi));
}

// Window fold tables: phi = pi*(2n+1)/2048, n in [0,256)
__global__ void build_window(float* __restrict__ wsin, float* __restrict__ wcos) {
  int n = threadIdx.x;
  float ph = PI_F * (float)(2 * n + 1) / 2048.0f;
  wsin[n] = sinf(ph);
  wcos[n] = cosf(ph);
}

// Truncation split of 8 fp32 -> bf16 hi + bf16 lo, packed via v_perm_b32.
// hi = trunc16(x), lo = trunc16(x - hi). Exact except <=2^-16 rel on lo.
__device__ __forceinline__ void split8(const float* u, bf16x8& vh, bf16x8& vl) {
  u32 h[8], lo[8];
#pragma unroll
  for (int j = 0; j < 8; ++j) {
    u32 x = __float_as_uint(u[j]);
    h[j] = x & 0xffff0000u;
    lo[j] = __float_as_uint(u[j] - __uint_as_float(h[j]));
  }
  union {
    u32 w[4];
    bf16x8 v;
  } H, L;
#pragma unroll
  for (int j = 0; j < 4; ++j) {
    H.w[j] = __builtin_amdgcn_perm(h[2 * j + 1], h[2 * j], 0x07060302u);
    L.w[j] = __builtin_amdgcn_perm(lo[2 * j + 1], lo[2 * j], 0x07060302u);
  }
  vh = H.v;
  vl = L.v;
}

// out[16000][512] = Af[16000][512] * Bf[512][512] (Bf stored [col][k]).
// Af[m][n<256]  = u_n = x[n]*sin(phi) - x[511-n]*cos(phi)
// Af[m][256+n]  = v_n = x[512+n]*cos(phi) + x[1023-n]*sin(phi)
// No LDS staging, no barriers: audio panel (512KB/block) and Bf table (1MB) are
// L2-resident; each wave loads its MFMA fragments straight to registers.
// Block = 128x128 tile, 4 waves 2x2 (64x64 each), K-loop = 16 steps of 32.
__global__ __launch_bounds__(256, 2) void mdct_mfma(
    const float* __restrict__ audio,
    const u16* __restrict__ bt_hi, const u16* __restrict__ bt_lo,
    const float* __restrict__ wsin_g, const float* __restrict__ wcos_g,
    float* __restrict__ out) {
  __shared__ float Wsin[256], Wcos[256];

  const int tid = threadIdx.x;
  const int lane = tid & 63;
  const int wid = tid >> 6;
  const int wr = wid >> 1, wcol = wid & 1;

  if (tid < 64)
    ((float4*)Wsin)[tid] = ((const float4*)wsin_g)[tid];
  else if (tid < 128)
    ((float4*)Wcos)[tid - 64] = ((const float4*)wcos_g)[tid - 64];
  __syncthreads();  // only barrier in the kernel

  // Bijective XCD swizzle (m204): 500 = 8*62+4.
  int orig = (int)blockIdx.x;
  int xcd = orig & 7, bidx = orig >> 3;
  int wgid = (xcd < 4 ? xcd * 63 : 252 + (xcd - 4) * 62) + bidx;
  const int m0 = (wgid >> 2) * 128;
  const int n0 = (wgid & 3) * 128;

  // Per-mi frame base (row = this lane's A-frag row, fixed all K).
  const float* ap[4];
  int fb[4];
#pragma unroll
  for (int mi = 0; mi < 4; ++mi) {
    int m = m0 + wr * 64 + mi * 16 + (lane & 15);
    int b = m / 1000, l = m - b * 1000;
    ap[mi] = audio + (size_t)b * NSAMP;
    fb[mi] = l * 512 - 256;
  }
  const int kc8 = (lane >> 4) * 8;  // lane's k-chunk within each 32-step

  // B fragment base pointers (col fixed all K).
  const u16 *bhp[4], *blp[4];
#pragma unroll
  for (int ni = 0; ni < 4; ++ni) {
    int col = n0 + wcol * 64 + ni * 16 + (lane & 15);
    bhp[ni] = bt_hi + (size_t)col * K2 + kc8;
    blp[ni] = bt_lo + (size_t)col * K2 + kc8;
  }

  f32x4 acc[4][4];
#pragma unroll
  for (int mi = 0; mi < 4; ++mi)
#pragma unroll
    for (int ni = 0; ni < 4; ++ni)
      acc[mi][ni] = (f32x4){0.f, 0.f, 0.f, 0.f};

  for (int t = 0; t < 16; ++t) {
    const bool isU = (t < 8);
    const int nc = (t & 7) * 32 + kc8;  // [0,256), multiple of 8

    // B fragments for this K-step (16B aligned, L2-hot).
    bf16x8 bh[4], bl[4];
#pragma unroll
    for (int ni = 0; ni < 4; ++ni) {
      bh[ni] = *(const bf16x8*)(bhp[ni] + t * 32);
      bl[ni] = *(const bf16x8*)(blp[ni] + t * 32);
    }

    // A raw loads: fwd + rev 32B chunks per mi, guarded (chunks never straddle).
    float4 f0[4], f1[4], r0[4], r1[4];
#pragma unroll
    for (int mi = 0; mi < 4; ++mi) {
      int tf = fb[mi] + (isU ? nc : 512 + nc);
      int tr = fb[mi] + (isU ? 504 - nc : 1016 - nc);
      float4 z = make_float4(0.f, 0.f, 0.f, 0.f);
      f0[mi] = z; f1[mi] = z; r0[mi] = z; r1[mi] = z;
      if ((unsigned)tf < (unsigned)NSAMP) {
        f0[mi] = *(const float4*)(ap[mi] + tf);
        f1[mi] = *(const float4*)(ap[mi] + tf + 4);
      }
      if ((unsigned)tr < (unsigned)NSAMP) {
        r0[mi] = *(const float4*)(ap[mi] + tr);
        r1[mi] = *(const float4*)(ap[mi] + tr + 4);
      }
    }

    // Window coefficients: u: xf*ws - xr*wc ; v: xf*wc + xr*ws  -> uniform FMA form.
    float wA[8], wB[8];
    {
      float4 s0 = *(const float4*)&Wsin[nc], s1 = *(const float4*)&Wsin[nc + 4];
      float4 c0 = *(const float4*)&Wcos[nc], c1 = *(const float4*)&Wcos[nc + 4];
      float ss[8] = {s0.x, s0.y, s0.z, s0.w, s1.x, s1.y, s1.z, s1.w};
      float cc[8] = {c0.x, c0.y, c0.z, c0.w, c1.x, c1.y, c1.z, c1.w};
#pragma unroll
      for (int j = 0; j < 8; ++j) {
        wA[j] = isU ? ss[j] : cc[j];
        wB[j] = isU ? -cc[j] : ss[j];
      }
    }

#pragma unroll
    for (int mi = 0; mi < 4; ++mi) {
      float xf[8] = {f0[mi].x, f0[mi].y, f0[mi].z, f0[mi].w,
                     f1[mi].x, f1[mi].y, f1[mi].z, f1[mi].w};
      float xr[8] = {r0[mi].x, r0[mi].y, r0[mi].z, r0[mi].w,
                     r1[mi].x, r1[mi].y, r1[mi].z, r1[mi].w};
      float u[8];
#pragma unroll
      for (int j = 0; j < 8; ++j)
        u[j] = fmaf(xf[j], wA[j], xr[7 - j] * wB[j]);  // rev chunk ascends: j <-> 7-j
      bf16x8 ah, al;
      split8(u, ah, al);
#pragma unroll
      for (int ni = 0; ni < 4; ++ni) {
        acc[mi][ni] = __builtin_amdgcn_mfma_f32_16x16x32_bf16(ah, bh[ni], acc[mi][ni], 0, 0, 0);
        acc[mi][ni] = __builtin_amdgcn_mfma_f32_16x16x32_bf16(ah, bl[ni], acc[mi][ni], 0, 0, 0);
        acc[mi][ni] = __builtin_amdgcn_mfma_f32_16x16x32_bf16(al, bh[ni], acc[mi][ni], 0, 0, 0);
      }
    }
  }

  // Epilogue: C/D layout col=lane&15, row=(lane>>4)*4+reg (HW-verified r2/r3).
#pragma unroll
  for (int mi = 0; mi < 4; ++mi) {
    int row0 = m0 + wr * 64 + mi * 16 + ((lane >> 4) << 2);
#pragma unroll
    for (int ni = 0; ni < 4; ++ni) {
      int col = n0 + wcol * 64 + ni * 16 + (lane & 15);
      float* p = out + (size_t)row0 * NKOUT + col;
      f32x4 v = acc[mi][ni];
      p[0] = v[0];
      p[NKOUT] = v[1];
      p[2 * NKOUT] = v[2];
      p[3 * NKOUT] = v[3];
    }
  }
}

// Correct-but-slow fallback (unfolded, fp32-exact) if workspace too small.
__global__ void mdct_naive(const float* __restrict__ audio, float* __restrict__ out) {
  int idx = blockIdx.x * 256 + threadIdx.x;
  if (idx >= MROWS * NKOUT) return;
  int k = idx & (NKOUT - 1);
  int m = idx >> 9;
  int b = m / 1000, l = m - b * 1000;
  const float* a = audio + (size_t)b * NSAMP;
  float s = 0.f;
  for (int n = 0; n < 1024; ++n) {
    int t = l * 512 + n - 256;
    float x = ((unsigned)t < (unsigned)NSAMP) ? a[t] : 0.f;
    float w = sinf(PI_F * (float)(2 * n + 1) / 2048.0f);
    int P = ((2 * n + 513) * (2 * k + 1)) & 4095;
    s += x * w * cosf(PI_F * (float)P / 2048.0f);
  }
  out[idx] = 0.0625f * s;
}

extern "C" void kernel_launch(void* const* d_in, const int* in_sizes, int n_in,
                              void* d_out, int out_size, void* d_ws, size_t ws_size,
                              hipStream_t stream) {
  const float* audio = (const float*)d_in[0];
  float* out = (float*)d_out;
  size_t tbl = (size_t)NKOUT * K2;
  size_t need = tbl * 2 * sizeof(u16) + 512 * sizeof(float);
  if (d_ws != nullptr && ws_size >= need) {
    u16* bt_hi = (u16*)d_ws;
    u16* bt_lo = bt_hi + tbl;
    float* wsin = (float*)(bt_lo + tbl);
    float* wcos = wsin + 256;
    build_basis<<<(NKOUT * K2) / 256, 256, 0, stream>>>(bt_hi, bt_lo);
    build_window<<<1, 256, 0, stream>>>(wsin, wcos);
    mdct_mfma<<<NBLK, 256, 0, stream>>>(audio, bt_hi, bt_lo, wsin, wcos, out);
  } else {
    mdct_naive<<<(MROWS * NKOUT + 255) / 256, 256, 0, stream>>>(audio, out);
  }
}

// Round 8
// 110.333 us; speedup vs baseline: 1.4902x; 1.4902x over previous
//
#include <hip/hip_runtime.h>
#include <stdint.h>

typedef unsigned short u16;
typedef uint32_t u32;
typedef short bf16x8 __attribute__((ext_vector_type(8)));
typedef float f32x4 __attribute__((ext_vector_type(4)));

#define PI_F 3.14159265358979323846f
#define NSAMP 512000
#define MROWS 16000
#define K2 512
#define NKOUT 512
#define NBLK 500

__device__ __forceinline__ u16 f2bf(float f) {
  uint32_t x = __float_as_uint(f);
  return (u16)((x + 0x7fffu + ((x >> 16) & 1u)) >> 16);  // RNE
}
__device__ __forceinline__ float bf2f(u16 u) {
  return __uint_as_float(((uint32_t)u) << 16);
}

// Folded basis Bf[k][m], k,m in [0,512). theta = pi*((2n+513)(2k+1) mod 4096)/2048, n=m&255.
// m<256: cos(theta); m>=256: -(-1)^k sin(theta). Scale 1/16 folded in. Split bf16 hi+lo.
__global__ void build_basis(u16* __restrict__ bt_hi, u16* __restrict__ bt_lo) {
  int idx = blockIdx.x * 256 + threadIdx.x;  // 512*512
  int k = idx >> 9, m = idx & 511;
  int n = m & 255;
  int P = ((2 * n + 513) * (2 * k + 1)) & 4095;
  float ang = PI_F * (float)P / 2048.0f;
  float v = (m < 256) ? cosf(ang) : ((k & 1) ? sinf(ang) : -sinf(ang));
  v *= 0.0625f;
  u16 hi = f2bf(v);
  bt_hi[idx] = hi;
  bt_lo[idx] = f2bf(v - bf2f(hi));
}

// Window fold tables: phi = pi*(2n+1)/2048, n in [0,256)
__global__ void build_window(float* __restrict__ wsin, float* __restrict__ wcos) {
  int n = threadIdx.x;
  float ph = PI_F * (float)(2 * n + 1) / 2048.0f;
  wsin[n] = sinf(ph);
  wcos[n] = cosf(ph);
}

// Truncation split of 8 fp32 -> bf16 hi + bf16 lo (HW-validated r6: passed).
__device__ __forceinline__ void split8(const float* u, bf16x8& vh, bf16x8& vl) {
  u32 h[8], lo[8];
#pragma unroll
  for (int j = 0; j < 8; ++j) {
    u32 x = __float_as_uint(u[j]);
    h[j] = x & 0xffff0000u;
    lo[j] = __float_as_uint(u[j] - __uint_as_float(h[j]));
  }
  union { u32 w[4]; bf16x8 v; } H, L;
#pragma unroll
  for (int j = 0; j < 4; ++j) {
    H.w[j] = __builtin_amdgcn_perm(h[2 * j + 1], h[2 * j], 0x07060302u);
    L.w[j] = __builtin_amdgcn_perm(lo[2 * j + 1], lo[2 * j], 0x07060302u);
  }
  vh = H.v;
  vl = L.v;
}

// Pass 1: window-fold + split. Af[m][k], k<256: u_n ; k>=256: v_n (n=k&255).
// u_n = x[n]*sin(phi) - x[511-n]*cos(phi); v_n = x[512+n]*cos(phi) + x[1023-n]*sin(phi).
// One thread per 8 k of one row; fully coalesced.
__global__ __launch_bounds__(256) void fold_split(
    const float* __restrict__ audio,
    const float* __restrict__ wsin_g, const float* __restrict__ wcos_g,
    u16* __restrict__ af_hi, u16* __restrict__ af_lo) {
  int gid = blockIdx.x * 256 + threadIdx.x;  // 16000*64
  int m = gid >> 6;
  int k0 = (gid & 63) * 8;
  bool isU = k0 < 256;
  int nc = k0 & 255;
  int b = m / 1000, l = m - b * 1000;
  const float* ap = audio + (size_t)b * NSAMP;
  int base = l * 512 - 256;
  int tf = base + (isU ? nc : 512 + nc);        // mult of 8 -> no straddle
  int tr = base + (isU ? 504 - nc : 1016 - nc); // mult of 8
  float4 z = make_float4(0.f, 0.f, 0.f, 0.f);
  float4 f0 = z, f1 = z, r0 = z, r1 = z;
  if ((unsigned)tf < (unsigned)NSAMP) {
    f0 = *(const float4*)(ap + tf);
    f1 = *(const float4*)(ap + tf + 4);
  }
  if ((unsigned)tr < (unsigned)NSAMP) {
    r0 = *(const float4*)(ap + tr);
    r1 = *(const float4*)(ap + tr + 4);
  }
  float4 s0 = *(const float4*)(wsin_g + nc), s1 = *(const float4*)(wsin_g + nc + 4);
  float4 c0 = *(const float4*)(wcos_g + nc), c1 = *(const float4*)(wcos_g + nc + 4);
  float xf[8] = {f0.x, f0.y, f0.z, f0.w, f1.x, f1.y, f1.z, f1.w};
  float xr[8] = {r0.x, r0.y, r0.z, r0.w, r1.x, r1.y, r1.z, r1.w};
  float ss[8] = {s0.x, s0.y, s0.z, s0.w, s1.x, s1.y, s1.z, s1.w};
  float cc[8] = {c0.x, c0.y, c0.z, c0.w, c1.x, c1.y, c1.z, c1.w};
  float u[8];
#pragma unroll
  for (int j = 0; j < 8; ++j) {
    float wA = isU ? ss[j] : cc[j];
    float wB = isU ? -cc[j] : ss[j];
    u[j] = fmaf(xf[j], wA, xr[7 - j] * wB);  // rev chunk ascends: j <-> 7-j
  }
  bf16x8 vh, vl;
  split8(u, vh, vl);
  size_t o = (size_t)m * K2 + k0;
  *(bf16x8*)(af_hi + o) = vh;
  *(bf16x8*)(af_lo + o) = vl;
}

__device__ __forceinline__ void gl_lds16(const u16* g, u16* l) {
  __builtin_amdgcn_global_load_lds(
      (const __attribute__((address_space(1))) uint32_t*)g,
      (__attribute__((address_space(3))) uint32_t*)l, 16, 0, 0);
}

// Pass 2: out[16000][512] = Af[16000][512] * Bf[512][512] (Bf stored [col][k]).
// 128x128 tile, BK=32, 4 waves 2x2 (64x64 each). Double-buffered LDS (64KB),
// ALL staging via global_load_lds (linear dest + pre-swizzled source, rule #21).
// Swizzle: 4 slots of 16B per 64B row; slot' = slot ^ ((row>>1)&3) -> 2-way (free).
// Schedule: T3-minimum — stage(t+1) issued BEFORE ds_read/MFMA(t); one barrier/iter.
__global__ __launch_bounds__(256, 2) void mdct_gemm(
    const u16* __restrict__ af_hi, const u16* __restrict__ af_lo,
    const u16* __restrict__ bt_hi, const u16* __restrict__ bt_lo,
    float* __restrict__ out) {
  __shared__ u16 lds[2][4][4096];  // [buf][Ahi,Alo,Bhi,Blo][128 rows x 32 k]

  const int tid = threadIdx.x;
  const int lane = tid & 63;
  const int wid = tid >> 6;
  const int wr = wid >> 1, wcol = wid & 1;

  // Bijective XCD swizzle (m204): 500 = 8*62+4.
  int orig = (int)blockIdx.x;
  int xcd = orig & 7, bidx = orig >> 3;
  int wgid = (xcd < 4 ? xcd * 63 : 252 + (xcd - 4) * 62) + bidx;
  const int m0 = (wgid >> 2) * 128;
  const int n0 = (wgid & 3) * 128;

  // Staging sources: chunk c = tid + 256*s -> (row=c>>2, slot=c&3), 8 elems; linear dest c*8.
  int asrc[2], bsrc[2];
#pragma unroll
  for (int s = 0; s < 2; ++s) {
    int c = tid + (s << 8);
    int row = c >> 2, slot = c & 3;
    int sw = slot ^ ((row >> 1) & 3);
    asrc[s] = (m0 + row) * K2 + sw * 8;
    bsrc[s] = (n0 + row) * K2 + sw * 8;
  }

  // Fragment read byte-offsets (within one 8KB matrix), constant over K.
  int aoff[4], boff[4];
#pragma unroll
  for (int mi = 0; mi < 4; ++mi) {
    int row = wr * 64 + mi * 16 + (lane & 15);
    aoff[mi] = row * 64 + ((((lane >> 4) ^ ((row >> 1) & 3))) << 4);
  }
#pragma unroll
  for (int ni = 0; ni < 4; ++ni) {
    int col = wcol * 64 + ni * 16 + (lane & 15);
    boff[ni] = col * 64 + ((((lane >> 4) ^ ((col >> 1) & 3))) << 4);
  }

  f32x4 acc[4][4];
#pragma unroll
  for (int mi = 0; mi < 4; ++mi)
#pragma unroll
    for (int ni = 0; ni < 4; ++ni)
      acc[mi][ni] = (f32x4){0.f, 0.f, 0.f, 0.f};

  auto STAGE = [&](int buf, int kk) {
#pragma unroll
    for (int s = 0; s < 2; ++s) {
      int c = tid + (s << 8);
      gl_lds16(af_hi + asrc[s] + kk, &lds[buf][0][c * 8]);
      gl_lds16(af_lo + asrc[s] + kk, &lds[buf][1][c * 8]);
      gl_lds16(bt_hi + bsrc[s] + kk, &lds[buf][2][c * 8]);
      gl_lds16(bt_lo + bsrc[s] + kk, &lds[buf][3][c * 8]);
    }
  };

  STAGE(0, 0);
  __syncthreads();  // drains vmcnt(0): buf0 ready

  for (int t = 0; t < 16; ++t) {
    const int cur = t & 1;
    if (t < 15) STAGE(cur ^ 1, (t + 1) * 32);  // issue next tile BEFORE compute

    bf16x8 ah[4], al[4], bh[4], bl[4];
#pragma unroll
    for (int mi = 0; mi < 4; ++mi) {
      ah[mi] = *(const bf16x8*)((const char*)&lds[cur][0][0] + aoff[mi]);
      al[mi] = *(const bf16x8*)((const char*)&lds[cur][1][0] + aoff[mi]);
    }
#pragma unroll
    for (int ni = 0; ni < 4; ++ni) {
      bh[ni] = *(const bf16x8*)((const char*)&lds[cur][2][0] + boff[ni]);
      bl[ni] = *(const bf16x8*)((const char*)&lds[cur][3][0] + boff[ni]);
    }
#pragma unroll
    for (int mi = 0; mi < 4; ++mi)
#pragma unroll
      for (int ni = 0; ni < 4; ++ni) {
        acc[mi][ni] = __builtin_amdgcn_mfma_f32_16x16x32_bf16(ah[mi], bh[ni], acc[mi][ni], 0, 0, 0);
        acc[mi][ni] = __builtin_amdgcn_mfma_f32_16x16x32_bf16(ah[mi], bl[ni], acc[mi][ni], 0, 0, 0);
        acc[mi][ni] = __builtin_amdgcn_mfma_f32_16x16x32_bf16(al[mi], bh[ni], acc[mi][ni], 0, 0, 0);
      }

    __syncthreads();  // all reads of lds[cur] done + stage writes into lds[cur^1] landed
  }

  // Epilogue: C/D layout col=lane&15, row=(lane>>4)*4+reg (HW-verified r2/r3/r6).
#pragma unroll
  for (int mi = 0; mi < 4; ++mi) {
    int row0 = m0 + wr * 64 + mi * 16 + ((lane >> 4) << 2);
#pragma unroll
    for (int ni = 0; ni < 4; ++ni) {
      int col = n0 + wcol * 64 + ni * 16 + (lane & 15);
      float* p = out + (size_t)row0 * NKOUT + col;
      f32x4 v = acc[mi][ni];
      p[0] = v[0];
      p[NKOUT] = v[1];
      p[2 * NKOUT] = v[2];
      p[3 * NKOUT] = v[3];
    }
  }
}

// ---- Middle fallback: round-3 fused kernel (measured 51 us, passed). ----
__global__ __launch_bounds__(256, 2) void mdct_fused(
    const float* __restrict__ audio,
    const u16* __restrict__ bt_hi, const u16* __restrict__ bt_lo,
    const float* __restrict__ wsin_g, const float* __restrict__ wcos_g,
    float* __restrict__ out) {
  __shared__ u16 Ahi[8192], Alo[8192], Bhi[8192], Blo[8192];
  __shared__ float Wsin[256], Wcos[256];
  const int tid = threadIdx.x;
  const int lane = tid & 63;
  const int wid = tid >> 6;
  const int wr = wid >> 1, wcol = wid & 1;
  int orig = (int)blockIdx.x;
  int xcd = orig & 7, bidx = orig >> 3;
  int wgid = (xcd < 4 ? xcd * 63 : 252 + (xcd - 4) * 62) + bidx;
  const int m0 = (wgid >> 2) * 128;
  const int n0 = (wgid & 3) * 128;
  if (tid < 64)
    ((float4*)Wsin)[tid] = ((const float4*)wsin_g)[tid];
  else if (tid < 128)
    ((float4*)Wcos)[tid - 64] = ((const float4*)wcos_g)[tid - 64];
  const float* aptr[4];
  int base_[4], sl8_[4], awoff_[4], beoff_[4], bdst_[4];
#pragma unroll
  for (int s = 0; s < 4; ++s) {
    int c = tid + 256 * s;
    int row = c >> 3, slot = c & 7;
    int m = m0 + row;
    int b = m / 1000, l = m - b * 1000;
    aptr[s] = audio + (size_t)b * NSAMP;
    base_[s] = l * 512 - 256;
    sl8_[s] = slot * 8;
    int sw = slot ^ (row & 7);
    awoff_[s] = row * 128 + sw * 16;
    beoff_[s] = (n0 + row) * K2 + sw * 8;
    bdst_[s] = c * 8;
  }
  f32x4 acc[4][4];
#pragma unroll
  for (int mi = 0; mi < 4; ++mi)
#pragma unroll
    for (int ni = 0; ni < 4; ++ni)
      acc[mi][ni] = (f32x4){0.f, 0.f, 0.f, 0.f};
  for (int kk = 0; kk < K2; kk += 64) {
    __syncthreads();
#pragma unroll
    for (int s = 0; s < 4; ++s) {
      gl_lds16(bt_hi + beoff_[s] + kk, Bhi + bdst_[s]);
      gl_lds16(bt_lo + beoff_[s] + kk, Blo + bdst_[s]);
    }
    const bool isU = (kk < 256);
#pragma unroll
    for (int s = 0; s < 4; ++s) {
      int n0c = kk + sl8_[s] - (isU ? 0 : 256);
      int tf = base_[s] + (isU ? n0c : 512 + n0c);
      int tr = base_[s] + (isU ? 504 - n0c : 1016 - n0c);
      float4 z = make_float4(0.f, 0.f, 0.f, 0.f);
      float4 f0 = z, f1 = z, r0 = z, r1 = z;
      if ((unsigned)tf < (unsigned)NSAMP) {
        f0 = *(const float4*)(aptr[s] + tf);
        f1 = *(const float4*)(aptr[s] + tf + 4);
      }
      if ((unsigned)tr < (unsigned)NSAMP) {
        r0 = *(const float4*)(aptr[s] + tr);
        r1 = *(const float4*)(aptr[s] + tr + 4);
      }
      float4 s0 = *(const float4*)&Wsin[n0c], s1 = *(const float4*)&Wsin[n0c + 4];
      float4 c0 = *(const float4*)&Wcos[n0c], c1 = *(const float4*)&Wcos[n0c + 4];
      float xf[8] = {f0.x, f0.y, f0.z, f0.w, f1.x, f1.y, f1.z, f1.w};
      float xr[8] = {r0.x, r0.y, r0.z, r0.w, r1.x, r1.y, r1.z, r1.w};
      float ss[8] = {s0.x, s0.y, s0.z, s0.w, s1.x, s1.y, s1.z, s1.w};
      float cc[8] = {c0.x, c0.y, c0.z, c0.w, c1.x, c1.y, c1.z, c1.w};
      float u[8];
#pragma unroll
      for (int j = 0; j < 8; ++j) {
        float wA = isU ? ss[j] : cc[j];
        float wB = isU ? -cc[j] : ss[j];
        u[j] = fmaf(xf[j], wA, xr[7 - j] * wB);
      }
      bf16x8 vh, vl;
      split8(u, vh, vl);
      *(bf16x8*)((char*)Ahi + awoff_[s]) = vh;
      *(bf16x8*)((char*)Alo + awoff_[s]) = vl;
    }
    __syncthreads();
#pragma unroll
    for (int kb = 0; kb < 2; ++kb) {
      bf16x8 ah[4], al[4], bh[4], bl[4];
#pragma unroll
      for (int mi = 0; mi < 4; ++mi) {
        int row = wr * 64 + mi * 16 + (lane & 15);
        int off = row * 128 + ((((kb << 2) | (lane >> 4)) ^ (row & 7)) << 4);
        ah[mi] = *(const bf16x8*)((const char*)Ahi + off);
        al[mi] = *(const bf16x8*)((const char*)Alo + off);
      }
#pragma unroll
      for (int ni = 0; ni < 4; ++ni) {
        int col = wcol * 64 + ni * 16 + (lane & 15);
        int off = col * 128 + ((((kb << 2) | (lane >> 4)) ^ (col & 7)) << 4);
        bh[ni] = *(const bf16x8*)((const char*)Bhi + off);
        bl[ni] = *(const bf16x8*)((const char*)Blo + off);
      }
#pragma unroll
      for (int mi = 0; mi < 4; ++mi)
#pragma unroll
        for (int ni = 0; ni < 4; ++ni) {
          acc[mi][ni] = __builtin_amdgcn_mfma_f32_16x16x32_bf16(ah[mi], bh[ni], acc[mi][ni], 0, 0, 0);
          acc[mi][ni] = __builtin_amdgcn_mfma_f32_16x16x32_bf16(ah[mi], bl[ni], acc[mi][ni], 0, 0, 0);
          acc[mi][ni] = __builtin_amdgcn_mfma_f32_16x16x32_bf16(al[mi], bh[ni], acc[mi][ni], 0, 0, 0);
        }
    }
  }
#pragma unroll
  for (int mi = 0; mi < 4; ++mi) {
    int row0 = m0 + wr * 64 + mi * 16 + ((lane >> 4) << 2);
#pragma unroll
    for (int ni = 0; ni < 4; ++ni) {
      int col = n0 + wcol * 64 + ni * 16 + (lane & 15);
      float* p = out + (size_t)row0 * NKOUT + col;
      f32x4 v = acc[mi][ni];
      p[0] = v[0];
      p[NKOUT] = v[1];
      p[2 * NKOUT] = v[2];
      p[3 * NKOUT] = v[3];
    }
  }
}

// Correct-but-slow last-resort fallback.
__global__ void mdct_naive(const float* __restrict__ audio, float* __restrict__ out) {
  int idx = blockIdx.x * 256 + threadIdx.x;
  if (idx >= MROWS * NKOUT) return;
  int k = idx & (NKOUT - 1);
  int m = idx >> 9;
  int b = m / 1000, l = m - b * 1000;
  const float* a = audio + (size_t)b * NSAMP;
  float s = 0.f;
  for (int n = 0; n < 1024; ++n) {
    int t = l * 512 + n - 256;
    float x = ((unsigned)t < (unsigned)NSAMP) ? a[t] : 0.f;
    float w = sinf(PI_F * (float)(2 * n + 1) / 2048.0f);
    int P = ((2 * n + 513) * (2 * k + 1)) & 4095;
    s += x * w * cosf(PI_F * (float)P / 2048.0f);
  }
  out[idx] = 0.0625f * s;
}

extern "C" void kernel_launch(void* const* d_in, const int* in_sizes, int n_in,
                              void* d_out, int out_size, void* d_ws, size_t ws_size,
                              hipStream_t stream) {
  const float* audio = (const float*)d_in[0];
  float* out = (float*)d_out;
  size_t tbl = (size_t)NKOUT * K2;                              // 262144 elems
  size_t need_mid = tbl * 2 * sizeof(u16) + 512 * sizeof(float);  // ~1.05 MB
  size_t af = (size_t)MROWS * K2;                               // 8.192M elems
  size_t need_full = need_mid + af * 2 * sizeof(u16);           // ~33.8 MB
  if (d_ws != nullptr && ws_size >= need_full) {
    u16* bt_hi = (u16*)d_ws;
    u16* bt_lo = bt_hi + tbl;
    float* wsin = (float*)(bt_lo + tbl);
    float* wcos = wsin + 256;
    u16* af_hi = (u16*)(wcos + 256);
    u16* af_lo = af_hi + af;
    build_basis<<<(NKOUT * K2) / 256, 256, 0, stream>>>(bt_hi, bt_lo);
    build_window<<<1, 256, 0, stream>>>(wsin, wcos);
    fold_split<<<(MROWS * 64) / 256, 256, 0, stream>>>(audio, wsin, wcos, af_hi, af_lo);
    mdct_gemm<<<NBLK, 256, 0, stream>>>(af_hi, af_lo, bt_hi, bt_lo, out);
  } else if (d_ws != nullptr && ws_size >= need_mid) {
    u16* bt_hi = (u16*)d_ws;
    u16* bt_lo = bt_hi + tbl;
    float* wsin = (float*)(bt_lo + tbl);
    float* wcos = wsin + 256;
    build_basis<<<(NKOUT * K2) / 256, 256, 0, stream>>>(bt_hi, bt_lo);
    build_window<<<1, 256, 0, stream>>>(wsin, wcos);
    mdct_fused<<<NBLK, 256, 0, stream>>>(audio, bt_hi, bt_lo, wsin, wcos, out);
  } else {
    mdct_naive<<<(MROWS * NKOUT + 255) / 256, 256, 0, stream>>>(audio, out);
  }
}